// Round 6
// baseline (299.336 us; speedup 1.0000x reference)
//
#include <hip/hip_runtime.h>
#include <hip/hip_bf16.h>
#include <math.h>

#define NB 64
#define NA 8732
#define NC 81
#define TOTAL (NB * NA)    /* 558848 */
#define APB 64             /* anchors per block */
#define TPB 256            /* threads per block: 4 threads per anchor */
#define NBLK (TOTAL / APB) /* 8732 */

// ws layout:
//   float conf_neg[TOTAL]
//   int   pos_count[NB]
//   float acc[3]           (2 = neg_topk_sum)
//   float block_loc[NBLK]
//   float block_pcs[NBLK]

__global__ void init_kernel(int* __restrict__ pos_count, float* __restrict__ acc) {
    const int t = threadIdx.x;
    if (t < NB) pos_count[t] = 0;
    else if (t < NB + 3) acc[t - NB] = 0.0f;
}

// quad_perm butterfly all-reduce within each 4-lane group (full-rate VALU)
__device__ __forceinline__ float quadsum(float x) {
    x += __int_as_float(__builtin_amdgcn_update_dpp(
        0, __float_as_int(x), 0xB1, 0xF, 0xF, true));   // [1,0,3,2]
    x += __int_as_float(__builtin_amdgcn_update_dpp(
        0, __float_as_int(x), 0x4E, 0xF, 0xF, true));   // [2,3,0,1]
    return x;
}

// 64-anchor tile (20.7 KB LDS) -> 7 blocks/CU: enough independent blocks per
// CU that some are always staging while others compute (phase overlap).
__global__ __launch_bounds__(TPB) void main_kernel(
    const float* __restrict__ scores, const float* __restrict__ boxes,
    const int* __restrict__ gt_labels, const float* __restrict__ gt_boxes,
    const int* __restrict__ mask, float* __restrict__ conf_neg,
    int* __restrict__ pos_count, float* __restrict__ block_loc,
    float* __restrict__ block_pcs)
{
    __shared__ float lds[APB * NC];   // 20736 B
    __shared__ float wredl[4], wredp[4];
    const int tid  = threadIdx.x;
    const int lane = tid & 63;
    const int wid  = tid >> 6;        // 4 waves
    const int base = blockIdx.x * APB;
    const int b0   = base / NA;       // block spans image b0 (maybe b0+1)

    // ---- staging: 1296 float4 = 5*256 + 16; all loads issued before use ----
    const float4* __restrict__ src = (const float4*)(scores + (size_t)base * NC);
    float4* dst = (float4*)lds;
    const float4 t0 = src[tid];
    const float4 t1 = src[tid + 256];
    const float4 t2 = src[tid + 512];
    const float4 t3 = src[tid + 768];
    const float4 t4 = src[tid + 1024];
    float4 t5;
    if (tid < 16) t5 = src[tid + 1280];
    dst[tid] = t0; dst[tid + 256] = t1; dst[tid + 512] = t2;
    dst[tid + 768] = t3; dst[tid + 1024] = t4;
    if (tid < 16) dst[tid + 1280] = t5;

    // ---- loc part, wave 0 only: lane owns anchor base+lane ----
    float loc = 0.0f;
    if (wid == 0) {
        const int a = base + lane;
        const int m = mask[a];
        if (m) {
            const float4 bx = *(const float4*)(boxes    + (size_t)a * 4);
            const float4 gb = *(const float4*)(gt_boxes + (size_t)a * 4);
            const float d0 = bx.x - gb.x, d1 = bx.y - gb.y;
            const float d2 = bx.z - gb.z, d3 = bx.w - gb.w;
            const float a0 = fabsf(d0), a1 = fabsf(d1), a2 = fabsf(d2), a3 = fabsf(d3);
            loc = (a0 < 1.f ? 0.5f * d0 * d0 : a0 - 0.5f)
                + (a1 < 1.f ? 0.5f * d1 * d1 : a1 - 0.5f)
                + (a2 < 1.f ? 0.5f * d2 * d2 : a2 - 0.5f)
                + (a3 < 1.f ? 0.5f * d3 * d3 : a3 - 0.5f);
        }
        const int img = a / NA - b0;               // 0 or 1
        const unsigned long long m0 = __ballot(m && img == 0);
        const unsigned long long m1 = __ballot(m && img == 1);
        if (lane == 0 && m0) atomicAdd(&pos_count[b0], (int)__popcll(m0));
        if (lane == 1 && m1) atomicAdd(&pos_count[b0 + 1], (int)__popcll(m1));
    }
    __syncthreads();

    // ---- CE: 4 threads per anchor, 20(+1) classes each ----
    const int al = tid >> 2;          // local anchor 0..63
    const int q  = tid & 3;
    const float* __restrict__ row = lds + al * NC;
    float e = 0.0f;
    #pragma unroll
    for (int j = 0; j < 20; ++j) e += __expf(row[q * 20 + j]);
    if (q == 3) e += __expf(row[80]);
    e = quadsum(e);                   // all 4 lanes hold sum(exp)

    float pcs = 0.0f;
    if (q == 0) {                     // leader: 16 lanes/wave, coalesced-ish I/O
        const int a = base + al;
        const int lab = gt_labels[a];
        const float c = __logf(e) - row[lab];
        const int m = mask[a];
        conf_neg[a] = m ? 0.f : c;
        pcs = m ? c : 0.f;
    }

    #pragma unroll
    for (int o = 32; o; o >>= 1) {
        loc += __shfl_down(loc, o);
        pcs += __shfl_down(pcs, o);
    }
    if (lane == 0) { wredl[wid] = loc; wredp[wid] = pcs; }
    __syncthreads();
    if (tid == 0) {
        block_loc[blockIdx.x] = wredl[0] + wredl[1] + wredl[2] + wredl[3];
        block_pcs[blockIdx.x] = wredp[0] + wredp[1] + wredp[2] + wredp[3];
    }
}

// One block per batch row. Exact k-th-largest via radix-256 select (4 passes)
// on float bit patterns (all values >= 0 so uint order == float order), then
// sum of top-k with exact tie handling.
__global__ __launch_bounds__(1024) void topk_kernel(
    const float* __restrict__ conf_neg, const int* __restrict__ pos_count,
    float* __restrict__ acc)
{
    __shared__ unsigned sv[NA];          // 34928 B
    __shared__ int whist[16][256];       // per-wave replicated histograms
    __shared__ int hist[256];
    __shared__ int   redi[16];
    __shared__ float redf[16];
    __shared__ unsigned spfx;
    __shared__ int skr;
    const int tid = threadIdx.x;
    const int wid = tid >> 6;
    const int b = blockIdx.x;
    const float* __restrict__ row = conf_neg + (size_t)b * NA;

    for (int i = tid; i < NA; i += 1024) sv[i] = __float_as_uint(row[i]);

    int k = 3 * pos_count[b];
    if (k <= 0) return;          // uniform per block: safe early-out
    if (k > NA) k = NA;
    __syncthreads();

    unsigned prefix = 0u;
    int kr = k;
    for (int shift = 24; shift >= 0; shift -= 8) {
        #pragma unroll
        for (int j = tid; j < 16 * 256; j += 1024) ((int*)whist)[j] = 0;
        __syncthreads();
        const unsigned himask = (shift == 24) ? 0u : (0xFFFFFFFFu << (shift + 8));
        for (int i = tid; i < NA; i += 1024) {
            const unsigned v = sv[i];
            if ((v & himask) == prefix)
                atomicAdd(&whist[wid][(v >> shift) & 255], 1);
        }
        __syncthreads();
        if (tid < 256) {
            int s = 0;
            #pragma unroll
            for (int w = 0; w < 16; ++w) s += whist[w][tid];
            hist[tid] = s;
        }
        __syncthreads();
        // suffix sum: hist[j] = count of values in bins >= j
        for (int off = 1; off < 256; off <<= 1) {
            int val = 0;
            if (tid < 256) val = hist[tid] + ((tid + off < 256) ? hist[tid + off] : 0);
            __syncthreads();
            if (tid < 256) hist[tid] = val;
            __syncthreads();
        }
        if (tid < 256) {
            const int sj  = hist[tid];
            const int sj1 = (tid < 255) ? hist[tid + 1] : 0;
            if (sj >= kr && sj1 < kr) {          // exactly one bin matches
                spfx = prefix | ((unsigned)tid << shift);
                skr  = kr - sj1;
            }
        }
        __syncthreads();
        prefix = spfx;
        kr = skr;
        __syncthreads();
    }
    // prefix == bits of the k-th largest value T.
    // sum = sum(v > T) + (k - count(v > T)) * T   (exact tie handling)
    float s = 0.0f; int cg = 0;
    for (int i = tid; i < NA; i += 1024) {
        const unsigned u = sv[i];
        if (u > prefix) { s += __uint_as_float(u); cg++; }
    }
    #pragma unroll
    for (int o = 32; o; o >>= 1) { s += __shfl_down(s, o); cg += __shfl_down(cg, o); }
    if ((tid & 63) == 0) { redf[wid] = s; redi[wid] = cg; }
    __syncthreads();
    if (tid == 0) {
        float ts = 0.f; int tc = 0;
        #pragma unroll
        for (int w = 0; w < 16; ++w) { ts += redf[w]; tc += redi[w]; }
        ts += (float)(k - tc) * __uint_as_float(prefix);
        atomicAdd(&acc[2], ts);   // 64 atomics total: negligible
    }
}

// Single block: reduce the 8732 per-block partials + pos_count, emit outputs.
__global__ __launch_bounds__(1024) void final_kernel(
    const float* __restrict__ block_loc, const float* __restrict__ block_pcs,
    const int* __restrict__ pos_count, const float* __restrict__ acc,
    float* __restrict__ out)
{
    __shared__ float rl[16], rp[16];
    const int tid = threadIdx.x;
    const int wid = tid >> 6;
    float sl = 0.f, sp = 0.f;
    for (int i = tid; i < NBLK; i += 1024) { sl += block_loc[i]; sp += block_pcs[i]; }
    int p = (tid < NB) ? pos_count[tid] : 0;
    #pragma unroll
    for (int o = 32; o; o >>= 1) {
        sl += __shfl_down(sl, o);
        sp += __shfl_down(sp, o);
        p  += __shfl_down(p, o);
    }
    if ((tid & 63) == 0) { rl[wid] = sl; rp[wid] = sp; }
    __syncthreads();
    if (tid == 0) {
        float tl = 0.f, tp = 0.f;
        #pragma unroll
        for (int w = 0; w < 16; ++w) { tl += rl[w]; tp += rp[w]; }
        const float N = fmaxf(1.0f, (float)p);   // p: wave-0 reduction of 64 counts
        const float loc  = tl / N;
        const float conf = (tp + acc[2]) / N;
        out[0] = loc + conf;
        out[1] = loc;
        out[2] = conf;
    }
}

extern "C" void kernel_launch(void* const* d_in, const int* in_sizes, int n_in,
                              void* d_out, int out_size, void* d_ws, size_t ws_size,
                              hipStream_t stream) {
    const float* scores    = (const float*)d_in[0];
    const float* boxes     = (const float*)d_in[1];
    const int*   gt_labels = (const int*)d_in[2];
    const float* gt_boxes  = (const float*)d_in[3];
    const int*   mask      = (const int*)d_in[4];
    float* out = (float*)d_out;

    float* conf_neg  = (float*)d_ws;
    int*   pos_count = (int*)(conf_neg + TOTAL);
    float* acc       = (float*)(pos_count + NB);
    float* block_loc = acc + 3;
    float* block_pcs = block_loc + NBLK;

    hipLaunchKernelGGL(init_kernel, dim3(1), dim3(128), 0, stream, pos_count, acc);
    hipLaunchKernelGGL(main_kernel, dim3(NBLK), dim3(TPB), 0, stream,
                       scores, boxes, gt_labels, gt_boxes, mask,
                       conf_neg, pos_count, block_loc, block_pcs);
    hipLaunchKernelGGL(topk_kernel, dim3(NB), dim3(1024), 0, stream,
                       conf_neg, pos_count, acc);
    hipLaunchKernelGGL(final_kernel, dim3(1), dim3(1024), 0, stream,
                       block_loc, block_pcs, pos_count, acc, out);
}